// Round 1
// baseline (2213.324 us; speedup 1.0000x reference)
//
#include <hip/hip_runtime.h>
#include <math.h>

// DCGRU cell, N=4096 nodes, B=32, IN_DIM=2, U=64, K=2, 2 supports, M=5.
// Supports are ~1% dense -> extract CSR each call, do SpMM instead of dense
// (567 GFLOP dense fp32 vector would be ~3.6ms; sparse is ~6 GFLOP).
// Internal layout: x[n][b*F + f], F=66, row length C=2112 floats.

#define NN 4096
#define BB 32
#define UU 64
#define FF 66
#define MM 5
#define CC (BB*FF)   // 2112
#define CAP 128      // max nnz per row (mean 41, sigma 6.4 -> 128 is ~13 sigma)

// ---------------- CSR extraction: one wave per row, order-preserving ----------
__global__ __launch_bounds__(256) void extract_csr(
    const float* __restrict__ S0, const float* __restrict__ S1,
    int* __restrict__ cols, float* __restrict__ vals, int* __restrict__ nnz) {
  int wave = threadIdx.x >> 6;
  int lane = threadIdx.x & 63;
  int row  = blockIdx.x * 4 + wave;
  int sup  = blockIdx.y;
  const float* srow = (sup ? S1 : S0) + (size_t)row * NN;
  int*   crow = cols + ((size_t)sup * NN + row) * CAP;
  float* vrow = vals + ((size_t)sup * NN + row) * CAP;
  int base = 0;
  for (int j0 = 0; j0 < NN; j0 += 64) {
    float v = srow[j0 + lane];
    unsigned long long mask = __ballot(v != 0.0f);
    if (v != 0.0f) {
      int pos = base + __popcll(mask & ((1ull << lane) - 1ull));
      if (pos < CAP) { crow[pos] = j0 + lane; vrow[pos] = v; }
    }
    base += __popcll(mask);
  }
  if (lane == 0) nnz[sup * NN + row] = (base < CAP) ? base : CAP;
}

// ---------------- build x0[n][b*F+f] from inputs (B,N*2) and hx (B,N*64) -----
__global__ __launch_bounds__(256) void build_x0(
    const float* __restrict__ inp, const float* __restrict__ hx,
    float* __restrict__ x0) {
  int n = blockIdx.x;
  for (int c = threadIdx.x; c < CC; c += 256) {
    int b = c / FF;
    int f = c - b * FF;
    float v = (f < 2) ? inp[(size_t)b * (NN * 2) + n * 2 + f]
                      : hx[(size_t)b * (NN * UU) + n * UU + (f - 2)];
    x0[(size_t)n * CC + c] = v;
  }
}

// ---------------- SpMM: y[row,:] = alpha * sum_k val*x[col,:]  (+ beta*z) ----
__global__ __launch_bounds__(256) void spmm_kernel(
    const int* __restrict__ cols, const float* __restrict__ vals,
    const int* __restrict__ nnz, const float* __restrict__ x,
    const float* __restrict__ z, float alpha, float beta,
    float* __restrict__ y) {
  __shared__ int   scol[CAP];
  __shared__ float sval[CAP];
  int row = blockIdx.x;
  int t = threadIdx.x;
  int cnt = nnz[row];
  if (t < CAP) {
    scol[t] = cols[(size_t)row * CAP + t];
    sval[t] = vals[(size_t)row * CAP + t];
  }
  __syncthreads();
  float4 a0 = make_float4(0.f, 0.f, 0.f, 0.f);
  float4 a1 = a0, a2 = a0;
  // C/4 = 528 float4s per row: t, t+256, (t<16: t+512)
  for (int k = 0; k < cnt; ++k) {
    const float4* xr = (const float4*)(x + (size_t)scol[k] * CC);
    float v = sval[k];
    float4 b0 = xr[t];
    float4 b1 = xr[t + 256];
    a0.x = fmaf(v, b0.x, a0.x); a0.y = fmaf(v, b0.y, a0.y);
    a0.z = fmaf(v, b0.z, a0.z); a0.w = fmaf(v, b0.w, a0.w);
    a1.x = fmaf(v, b1.x, a1.x); a1.y = fmaf(v, b1.y, a1.y);
    a1.z = fmaf(v, b1.z, a1.z); a1.w = fmaf(v, b1.w, a1.w);
    if (t < 16) {
      float4 b2 = xr[t + 512];
      a2.x = fmaf(v, b2.x, a2.x); a2.y = fmaf(v, b2.y, a2.y);
      a2.z = fmaf(v, b2.z, a2.z); a2.w = fmaf(v, b2.w, a2.w);
    }
  }
  float4* yr = (float4*)(y + (size_t)row * CC);
  if (z != nullptr) {
    const float4* zr = (const float4*)(z + (size_t)row * CC);
    float4 z0 = zr[t], z1 = zr[t + 256];
    float4 r0, r1;
    r0.x = alpha * a0.x + beta * z0.x; r0.y = alpha * a0.y + beta * z0.y;
    r0.z = alpha * a0.z + beta * z0.z; r0.w = alpha * a0.w + beta * z0.w;
    r1.x = alpha * a1.x + beta * z1.x; r1.y = alpha * a1.y + beta * z1.y;
    r1.z = alpha * a1.z + beta * z1.z; r1.w = alpha * a1.w + beta * z1.w;
    yr[t] = r0; yr[t + 256] = r1;
    if (t < 16) {
      float4 z2 = zr[t + 512], r2;
      r2.x = alpha * a2.x + beta * z2.x; r2.y = alpha * a2.y + beta * z2.y;
      r2.z = alpha * a2.z + beta * z2.z; r2.w = alpha * a2.w + beta * z2.w;
      yr[t + 512] = r2;
    }
  } else {
    float4 r0, r1;
    r0.x = alpha * a0.x; r0.y = alpha * a0.y; r0.z = alpha * a0.z; r0.w = alpha * a0.w;
    r1.x = alpha * a1.x; r1.y = alpha * a1.y; r1.z = alpha * a1.z; r1.w = alpha * a1.w;
    yr[t] = r0; yr[t + 256] = r1;
    if (t < 16) {
      float4 r2;
      r2.x = alpha * a2.x; r2.y = alpha * a2.y; r2.z = alpha * a2.z; r2.w = alpha * a2.w;
      yr[t + 512] = r2;
    }
  }
}

__device__ __forceinline__ float sigmoidf_(float x) {
  return 1.0f / (1.0f + __expf(-x));
}
__device__ __forceinline__ float tanhf_(float x) {
  x = fminf(fmaxf(x, -15.f), 15.f);
  float e = __expf(2.f * x);
  return (e - 1.f) / (e + 1.f);
}

// ---------------- gate GEMM: per n, out[b,o] = sigmoid(sum_{f,m} x*W + bias) -
// o in [0,128). r = o<64 -> writes x0p[n][b*F+2+o] = r*hx ; u -> ubuf row.
// x0p aliases mat0's buffer (safe: row n staged to LDS before overwrite).
// ubuf aliases mat1's buffer rows (2048 <= 2112 floats per row).
__global__ __launch_bounds__(256) void gate_kernel(
    const float* m0, const float* m1,
    const float* __restrict__ m2, const float* __restrict__ m3,
    const float* __restrict__ m4,
    const float* __restrict__ W, const float* __restrict__ bias,
    const float* __restrict__ hx, const float* __restrict__ inp,
    float* x0p, float* ubuf) {
  __shared__ float lds[MM][CC];
  int n = blockIdx.x;
  for (int c = threadIdx.x; c < CC; c += 256) {
    lds[0][c] = m0[(size_t)n * CC + c];
    lds[1][c] = m1[(size_t)n * CC + c];
    lds[2][c] = m2[(size_t)n * CC + c];
    lds[3][c] = m3[(size_t)n * CC + c];
    lds[4][c] = m4[(size_t)n * CC + c];
  }
  __syncthreads();
  int o = threadIdx.x & 127;
  int bg = threadIdx.x >> 7;  // 0..1, wave-uniform
  float acc[16];
  float bia = bias[o];
#pragma unroll
  for (int j = 0; j < 16; ++j) acc[j] = bia;
  for (int f = 0; f < FF; f += 2) {
#pragma unroll
    for (int m = 0; m < MM; ++m) {
      float w0 = W[((f) * MM + m) * 128 + o];
      float w1 = W[((f + 1) * MM + m) * 128 + o];
#pragma unroll
      for (int j = 0; j < 16; ++j) {
        int b = bg * 16 + j;
        float2 xv = *(const float2*)&lds[m][b * FF + f];  // wave-uniform bcast
        acc[j] = fmaf(xv.x, w0, fmaf(xv.y, w1, acc[j]));
      }
    }
  }
#pragma unroll
  for (int j = 0; j < 16; ++j) {
    int b = bg * 16 + j;
    float s = sigmoidf_(acc[j]);
    if (o < UU) {
      float rh = s * hx[(size_t)b * (NN * UU) + n * UU + o];
      x0p[(size_t)n * CC + b * FF + 2 + o] = rh;
    } else {
      ubuf[(size_t)n * CC + b * UU + (o - UU)] = s;
    }
  }
  if (threadIdx.x < BB * 2) {
    int b = threadIdx.x >> 1, f = threadIdx.x & 1;
    x0p[(size_t)n * CC + b * FF + f] = inp[(size_t)b * (NN * 2) + n * 2 + f];
  }
}

// ---------------- candidate GEMM + final combine ------------------------------
__global__ __launch_bounds__(256) void cand_kernel(
    const float* __restrict__ m0, const float* __restrict__ m1,
    const float* __restrict__ m2, const float* __restrict__ m3,
    const float* __restrict__ m4,
    const float* __restrict__ W2, const float* __restrict__ b2,
    const float* __restrict__ hx, const float* __restrict__ ubuf,
    float* __restrict__ out) {
  __shared__ float lds[MM][CC];
  int n = blockIdx.x;
  for (int c = threadIdx.x; c < CC; c += 256) {
    lds[0][c] = m0[(size_t)n * CC + c];
    lds[1][c] = m1[(size_t)n * CC + c];
    lds[2][c] = m2[(size_t)n * CC + c];
    lds[3][c] = m3[(size_t)n * CC + c];
    lds[4][c] = m4[(size_t)n * CC + c];
  }
  __syncthreads();
  int o = threadIdx.x & 63;
  int bg = threadIdx.x >> 6;  // 0..3, wave-uniform
  float acc[8];
  float bia = b2[o];
#pragma unroll
  for (int j = 0; j < 8; ++j) acc[j] = bia;
  for (int f = 0; f < FF; f += 2) {
#pragma unroll
    for (int m = 0; m < MM; ++m) {
      float w0 = W2[((f) * MM + m) * UU + o];
      float w1 = W2[((f + 1) * MM + m) * UU + o];
#pragma unroll
      for (int j = 0; j < 8; ++j) {
        int b = bg * 8 + j;
        float2 xv = *(const float2*)&lds[m][b * FF + f];
        acc[j] = fmaf(xv.x, w0, fmaf(xv.y, w1, acc[j]));
      }
    }
  }
#pragma unroll
  for (int j = 0; j < 8; ++j) {
    int b = bg * 8 + j;
    float c = tanhf_(acc[j]);
    float uu = ubuf[(size_t)n * CC + b * UU + o];
    float h = hx[(size_t)b * (NN * UU) + n * UU + o];
    out[(size_t)b * (NN * UU) + n * UU + o] = uu * h + (1.0f - uu) * c;
  }
}

extern "C" void kernel_launch(void* const* d_in, const int* in_sizes, int n_in,
                              void* d_out, int out_size, void* d_ws, size_t ws_size,
                              hipStream_t stream) {
  const float* inp  = (const float*)d_in[0];
  const float* hx   = (const float*)d_in[1];
  const float* S0   = (const float*)d_in[2];
  const float* S1   = (const float*)d_in[3];
  const float* W    = (const float*)d_in[4];
  const float* bias = (const float*)d_in[5];
  const float* W2   = (const float*)d_in[6];
  const float* b2   = (const float*)d_in[7];
  float* out = (float*)d_out;

  float* ws = (float*)d_ws;
  const size_t MATSZ = (size_t)NN * CC;  // 8,650,752 floats
  float* bufA = ws;               // x0 -> x0'
  float* bufB = bufA + MATSZ;     // x1_0 -> u storage
  float* bufC = bufB + MATSZ;     // x2_0 -> x1_0'
  float* bufD = bufC + MATSZ;     // x1_1 -> x2_0'
  float* bufE = bufD + MATSZ;     // x2_1 -> x1_1'
  float* bufF = bufE + MATSZ;     // x2_1'
  int*   cols = (int*)(bufF + MATSZ);            // 2*N*CAP ints
  float* vals = (float*)(cols + 2 * (size_t)NN * CAP);
  int*   nnzA = (int*)(vals + 2 * (size_t)NN * CAP);  // 2*N ints
  const size_t NCAP = (size_t)NN * CAP;

  extract_csr<<<dim3(NN / 4, 2), 256, 0, stream>>>(S0, S1, cols, vals, nnzA);
  build_x0<<<NN, 256, 0, stream>>>(inp, hx, bufA);

  // gconv1 diffusion: x1_0, x2_0, x1_1, x2_1
  spmm_kernel<<<NN, 256, 0, stream>>>(cols, vals, nnzA, bufA, nullptr, 1.f, 0.f, bufB);
  spmm_kernel<<<NN, 256, 0, stream>>>(cols, vals, nnzA, bufB, bufA, 2.f, -1.f, bufC);
  spmm_kernel<<<NN, 256, 0, stream>>>(cols + NCAP, vals + NCAP, nnzA + NN, bufA, nullptr, 1.f, 0.f, bufD);
  spmm_kernel<<<NN, 256, 0, stream>>>(cols + NCAP, vals + NCAP, nnzA + NN, bufD, bufA, 2.f, -1.f, bufE);

  // gate: r,u ; x0' (in-place into bufA), u into bufB rows
  gate_kernel<<<NN, 256, 0, stream>>>(bufA, bufB, bufC, bufD, bufE, W, bias, hx, inp, bufA, bufB);

  // gconv2 diffusion on x0' = concat(inputs, r*hx)
  spmm_kernel<<<NN, 256, 0, stream>>>(cols, vals, nnzA, bufA, nullptr, 1.f, 0.f, bufC);
  spmm_kernel<<<NN, 256, 0, stream>>>(cols, vals, nnzA, bufC, bufA, 2.f, -1.f, bufD);
  spmm_kernel<<<NN, 256, 0, stream>>>(cols + NCAP, vals + NCAP, nnzA + NN, bufA, nullptr, 1.f, 0.f, bufE);
  spmm_kernel<<<NN, 256, 0, stream>>>(cols + NCAP, vals + NCAP, nnzA + NN, bufE, bufA, 2.f, -1.f, bufF);

  // candidate + final combine
  cand_kernel<<<NN, 256, 0, stream>>>(bufA, bufC, bufD, bufE, bufF, W2, b2, hx, bufB, out);
}

// Round 2
// 920.197 us; speedup vs baseline: 2.4053x; 2.4053x over previous
//
#include <hip/hip_runtime.h>
#include <math.h>

// DCGRU cell, N=4096, B=32, IN_DIM=2, U=64, K=2, 2 supports, M=5.
// R2: bf16 diffusion matrices (halves SpMM LLC gather traffic) +
//     MFMA gate/cand GEMMs (replaces LDS-broadcast-bound fp32 vector GEMM).
// Internal layout: x[n][b*F+f] bf16, F=66, row = 2112 elements = 4224 B.

#define NN 4096
#define BB 32
#define UU 64
#define FF 66
#define MM 5
#define CC (BB*FF)     // 2112
#define CAP 128        // max nnz/row (mean ~41)
#define KPAD 360       // LDS/W row stride in bf16 (>=352=11*32, 720B = 45*16B aligned)
#define KSTEPS 11      // 11 * 32 = 352 >= 330

typedef unsigned short u16;
typedef __attribute__((ext_vector_type(8))) short short8;
typedef __attribute__((ext_vector_type(4))) float float4v;

__device__ __forceinline__ u16 f2bf(float f) {
  unsigned u = __float_as_uint(f);
  u += 0x7FFFu + ((u >> 16) & 1u);   // RNE
  return (u16)(u >> 16);
}
__device__ __forceinline__ unsigned pack2(float lo, float hi) {
  return (unsigned)f2bf(lo) | ((unsigned)f2bf(hi) << 16);
}
__device__ __forceinline__ float bflo(unsigned d) { return __uint_as_float(d << 16); }
__device__ __forceinline__ float bfhi(unsigned d) { return __uint_as_float(d & 0xFFFF0000u); }

__device__ __forceinline__ float sigmoidf_(float x) {
  return 1.0f / (1.0f + __expf(-x));
}
__device__ __forceinline__ float tanhf_(float x) {
  x = fminf(fmaxf(x, -15.f), 15.f);
  float e = __expf(2.f * x);
  return (e - 1.f) / (e + 1.f);
}

// ---------------- CSR extraction: one wave per row, order-preserving ---------
__global__ __launch_bounds__(256) void extract_csr(
    const float* __restrict__ S0, const float* __restrict__ S1,
    int* __restrict__ cols, float* __restrict__ vals, int* __restrict__ nnz) {
  int wave = threadIdx.x >> 6;
  int lane = threadIdx.x & 63;
  int row  = blockIdx.x * 4 + wave;
  int sup  = blockIdx.y;
  const float* srow = (sup ? S1 : S0) + (size_t)row * NN;
  int*   crow = cols + ((size_t)sup * NN + row) * CAP;
  float* vrow = vals + ((size_t)sup * NN + row) * CAP;
  int base = 0;
  for (int j0 = 0; j0 < NN; j0 += 64) {
    float v = srow[j0 + lane];
    unsigned long long mask = __ballot(v != 0.0f);
    if (v != 0.0f) {
      int pos = base + __popcll(mask & ((1ull << lane) - 1ull));
      if (pos < CAP) { crow[pos] = j0 + lane; vrow[pos] = v; }
    }
    base += __popcll(mask);
  }
  if (lane == 0) nnz[sup * NN + row] = (base < CAP) ? base : CAP;
}

// ---------------- weight prep: W (330,128) -> Wt[o][k=m*66+f] bf16, pad 0 ----
__global__ __launch_bounds__(256) void prep_w(
    const float* __restrict__ W, const float* __restrict__ W2,
    u16* __restrict__ Wt, u16* __restrict__ W2t) {
  int idx = blockIdx.x * 256 + threadIdx.x;
  if (idx < 128 * KPAD) {
    int o = idx / KPAD, k = idx - o * KPAD;
    float v = 0.f;
    if (k < 330) { int m = k / FF, f = k - m * FF; v = W[((size_t)f * MM + m) * 128 + o]; }
    Wt[(size_t)o * KPAD + k] = f2bf(v);
  } else if (idx < 192 * KPAD) {
    int i = idx - 128 * KPAD;
    int o = i / KPAD, k = i - o * KPAD;
    float v = 0.f;
    if (k < 330) { int m = k / FF, f = k - m * FF; v = W2[((size_t)f * MM + m) * UU + o]; }
    W2t[(size_t)o * KPAD + k] = f2bf(v);
  }
}

// ---------------- build x0[n][b*F+f] bf16 ------------------------------------
__global__ __launch_bounds__(256) void build_x0(
    const float* __restrict__ inp, const float* __restrict__ hx,
    u16* __restrict__ x0) {
  int n = blockIdx.x;
  for (int c = threadIdx.x; c < CC; c += 256) {
    int b = c / FF;
    int f = c - b * FF;
    float v = (f < 2) ? inp[(size_t)b * (NN * 2) + n * 2 + f]
                      : hx[(size_t)b * (NN * UU) + n * UU + (f - 2)];
    x0[(size_t)n * CC + c] = f2bf(v);
  }
}

// ---------------- SpMM (bf16): grid (N, 2 supports) --------------------------
// out_sup[row,:] = alpha * sum_k val * xsrc_sup[col,:]  (+ beta * z[row,:])
__device__ __forceinline__ void fma8(float v, uint4 q, float* a) {
  a[0] = fmaf(v, bflo(q.x), a[0]); a[1] = fmaf(v, bfhi(q.x), a[1]);
  a[2] = fmaf(v, bflo(q.y), a[2]); a[3] = fmaf(v, bfhi(q.y), a[3]);
  a[4] = fmaf(v, bflo(q.z), a[4]); a[5] = fmaf(v, bfhi(q.z), a[5]);
  a[6] = fmaf(v, bflo(q.w), a[6]); a[7] = fmaf(v, bfhi(q.w), a[7]);
}
__device__ __forceinline__ uint4 emit8(const float* a, const uint4* zc,
                                       float alpha, float beta, bool hasz) {
  float r[8];
#pragma unroll
  for (int i = 0; i < 8; ++i) r[i] = alpha * a[i];
  if (hasz) {
    uint4 zq = *zc;
    r[0] += beta * bflo(zq.x); r[1] += beta * bfhi(zq.x);
    r[2] += beta * bflo(zq.y); r[3] += beta * bfhi(zq.y);
    r[4] += beta * bflo(zq.z); r[5] += beta * bfhi(zq.z);
    r[6] += beta * bflo(zq.w); r[7] += beta * bfhi(zq.w);
  }
  uint4 o;
  o.x = pack2(r[0], r[1]); o.y = pack2(r[2], r[3]);
  o.z = pack2(r[4], r[5]); o.w = pack2(r[6], r[7]);
  return o;
}

__global__ __launch_bounds__(256) void spmm_bf16(
    const int* __restrict__ cols, const float* __restrict__ vals,
    const int* __restrict__ nnz,
    const u16* __restrict__ x0src, const u16* __restrict__ x1src,
    const u16* __restrict__ z, float alpha, float beta,
    u16* __restrict__ out0, u16* __restrict__ out1) {
  __shared__ int   scol[CAP];
  __shared__ float sval[CAP];
  int row = blockIdx.x;
  int sup = blockIdx.y;
  const u16* xs = sup ? x1src : x0src;
  u16* out = sup ? out1 : out0;
  int t = threadIdx.x;
  int cnt = nnz[sup * NN + row];
  if (t < CAP) {
    scol[t] = cols[((size_t)sup * NN + row) * CAP + t];
    sval[t] = vals[((size_t)sup * NN + row) * CAP + t];
  }
  __syncthreads();
  float a[8], a2[8];
#pragma unroll
  for (int i = 0; i < 8; ++i) { a[i] = 0.f; a2[i] = 0.f; }
  bool extra = t < (CC / 8 - 256);   // 264 chunks of 8 bf16; t<8 take a second
  for (int k = 0; k < cnt; ++k) {
    const uint4* xr = (const uint4*)(xs + (size_t)scol[k] * CC);
    float v = sval[k];
    uint4 q = xr[t];
    fma8(v, q, a);
    if (extra) { uint4 q2 = xr[t + 256]; fma8(v, q2, a2); }
  }
  uint4* orow = (uint4*)(out + (size_t)row * CC);
  const uint4* zr = (const uint4*)(z ? (z + (size_t)row * CC) : nullptr);
  bool hasz = (z != nullptr);
  orow[t] = emit8(a, hasz ? (zr + t) : nullptr, alpha, beta, hasz);
  if (extra) orow[t + 256] = emit8(a2, hasz ? (zr + t + 256) : nullptr, alpha, beta, hasz);
}

// ---------------- shared staging for MFMA GEMMs ------------------------------
// lds layout: lx[b][k], k = m*66+f, row stride KPAD bf16; pad k in [330,360) = 0
__device__ __forceinline__ void stage_mats(
    u16* lx, int n,
    const u16* m0, const u16* m1, const u16* m2, const u16* m3, const u16* m4) {
#pragma unroll
  for (int m = 0; m < MM; ++m) {
    const u16* src = (m == 0) ? m0 : (m == 1) ? m1 : (m == 2) ? m2 : (m == 3) ? m3 : m4;
    const unsigned* s = (const unsigned*)(src + (size_t)n * CC);
    for (int i = threadIdx.x; i < BB * 33; i += 256) {   // 33 dwords per b
      int b = i / 33, d = i - b * 33;
      *(unsigned*)&lx[b * KPAD + m * FF + 2 * d] = s[b * 33 + d];
    }
  }
  for (int i = threadIdx.x; i < BB * 15; i += 256) {     // zero k 330..360
    int b = i / 15, d = i - b * 15;
    *(unsigned*)&lx[b * KPAD + 330 + 2 * d] = 0u;
  }
}

// ---------------- gate: D[b][o] = sigmoid(x @ W + bias), o in [0,128) --------
// o<64: write r*hx into x0p (bf16, aliases mat0 buffer row n); o>=64: u -> ubuf
__global__ __launch_bounds__(256) void gate_mfma(
    const u16* __restrict__ m0, const u16* __restrict__ m1,
    const u16* __restrict__ m2, const u16* __restrict__ m3,
    const u16* __restrict__ m4,
    const u16* __restrict__ Wt, const float* __restrict__ bias,
    const float* __restrict__ hx,
    u16* __restrict__ x0p, float* __restrict__ ubuf) {
  __shared__ u16 lx[BB * KPAD];
  int n = blockIdx.x;
  stage_mats(lx, n, m0, m1, m2, m3, m4);
  __syncthreads();
  int lane = threadIdx.x & 63;
  int w = threadIdx.x >> 6;
  int Mtile = w & 1;
  int Nbase = (w >> 1) * 4;          // 4 N-tiles per wave, 8 total (o=128)
  int colo = lane & 15;
  int quad = lane >> 4;
  float4v acc[4];
#pragma unroll
  for (int t = 0; t < 4; ++t) {
    float bv = bias[(Nbase + t) * 16 + colo];
    acc[t] = (float4v){bv, bv, bv, bv};
  }
  const u16* arow = &lx[(Mtile * 16 + colo) * KPAD];
  for (int ks = 0; ks < KSTEPS; ++ks) {
    short8 af = *(const short8*)(arow + ks * 32 + quad * 8);
#pragma unroll
    for (int t = 0; t < 4; ++t) {
      const u16* wrow = Wt + (size_t)((Nbase + t) * 16 + colo) * KPAD + ks * 32 + quad * 8;
      short8 bf = *(const short8*)wrow;
      acc[t] = __builtin_amdgcn_mfma_f32_16x16x32_bf16(af, bf, acc[t], 0, 0, 0);
    }
  }
  int brow0 = Mtile * 16 + quad * 4;
#pragma unroll
  for (int t = 0; t < 4; ++t) {
    int o = (Nbase + t) * 16 + colo;
#pragma unroll
    for (int r = 0; r < 4; ++r) {
      int b = brow0 + r;
      float s = sigmoidf_(acc[t][r]);
      if (o < UU) {
        float h = hx[(size_t)b * (NN * UU) + (size_t)n * UU + o];
        x0p[(size_t)n * CC + b * FF + 2 + o] = f2bf(s * h);
      } else {
        ubuf[(size_t)n * (BB * UU) + b * UU + (o - UU)] = s;
      }
    }
  }
}

// ---------------- candidate + final combine ----------------------------------
__global__ __launch_bounds__(256) void cand_mfma(
    const u16* __restrict__ m0, const u16* __restrict__ m1,
    const u16* __restrict__ m2, const u16* __restrict__ m3,
    const u16* __restrict__ m4,
    const u16* __restrict__ W2t, const float* __restrict__ b2,
    const float* __restrict__ hx, const float* __restrict__ ubuf,
    float* __restrict__ out) {
  __shared__ u16 lx[BB * KPAD];
  int n = blockIdx.x;
  stage_mats(lx, n, m0, m1, m2, m3, m4);
  __syncthreads();
  int lane = threadIdx.x & 63;
  int w = threadIdx.x >> 6;
  int Mtile = w & 1;
  int Nbase = (w >> 1) * 2;          // 2 N-tiles per wave, 4 total (o=64)
  int colo = lane & 15;
  int quad = lane >> 4;
  float4v acc[2];
#pragma unroll
  for (int t = 0; t < 2; ++t) {
    float bv = b2[(Nbase + t) * 16 + colo];
    acc[t] = (float4v){bv, bv, bv, bv};
  }
  const u16* arow = &lx[(Mtile * 16 + colo) * KPAD];
  for (int ks = 0; ks < KSTEPS; ++ks) {
    short8 af = *(const short8*)(arow + ks * 32 + quad * 8);
#pragma unroll
    for (int t = 0; t < 2; ++t) {
      const u16* wrow = W2t + (size_t)((Nbase + t) * 16 + colo) * KPAD + ks * 32 + quad * 8;
      short8 bf = *(const short8*)wrow;
      acc[t] = __builtin_amdgcn_mfma_f32_16x16x32_bf16(af, bf, acc[t], 0, 0, 0);
    }
  }
  int brow0 = Mtile * 16 + quad * 4;
#pragma unroll
  for (int t = 0; t < 2; ++t) {
    int o = (Nbase + t) * 16 + colo;
#pragma unroll
    for (int r = 0; r < 4; ++r) {
      int b = brow0 + r;
      float c = tanhf_(acc[t][r]);
      float u = ubuf[(size_t)n * (BB * UU) + b * UU + o];
      float h = hx[(size_t)b * (NN * UU) + (size_t)n * UU + o];
      out[(size_t)b * (NN * UU) + (size_t)n * UU + o] = u * h + (1.0f - u) * c;
    }
  }
}

extern "C" void kernel_launch(void* const* d_in, const int* in_sizes, int n_in,
                              void* d_out, int out_size, void* d_ws, size_t ws_size,
                              hipStream_t stream) {
  const float* inp  = (const float*)d_in[0];
  const float* hx   = (const float*)d_in[1];
  const float* S0   = (const float*)d_in[2];
  const float* S1   = (const float*)d_in[3];
  const float* W    = (const float*)d_in[4];
  const float* bias = (const float*)d_in[5];
  const float* W2   = (const float*)d_in[6];
  const float* b2   = (const float*)d_in[7];
  float* out = (float*)d_out;

  char* ws = (char*)d_ws;
  const size_t MATB = (size_t)NN * CC * sizeof(u16);   // 17,301,504 B
  u16* bufA = (u16*)(ws);                  // x0 -> x0'
  u16* bufB = (u16*)(ws + 1 * MATB);       // S0@x0
  u16* bufC = (u16*)(ws + 2 * MATB);       // cheb(S0) -> S0@x0'
  u16* bufD = (u16*)(ws + 3 * MATB);       // S1@x0   -> cheb(S0)'
  u16* bufE = (u16*)(ws + 4 * MATB);       // cheb(S1) -> S1@x0'
  u16* bufF = (u16*)(ws + 5 * MATB);       // cheb(S1)'
  char* p = ws + 6 * MATB;
  float* ubuf = (float*)p;                 p += (size_t)NN * BB * UU * 4;   // 33.5 MB
  int*   cols = (int*)p;                   p += 2 * (size_t)NN * CAP * 4;
  float* vals = (float*)p;                 p += 2 * (size_t)NN * CAP * 4;
  int*   nnzA = (int*)p;                   p += 2 * (size_t)NN * 4;
  u16*   Wt   = (u16*)p;                   p += (size_t)128 * KPAD * 2;
  u16*   W2t  = (u16*)p;

  prep_w<<<(192 * KPAD + 255) / 256, 256, 0, stream>>>(W, W2, Wt, W2t);
  extract_csr<<<dim3(NN / 4, 2), 256, 0, stream>>>(S0, S1, cols, vals, nnzA);
  build_x0<<<NN, 256, 0, stream>>>(inp, hx, bufA);

  // gconv1 diffusion: hop1 both supports, then Chebyshev both supports
  spmm_bf16<<<dim3(NN, 2), 256, 0, stream>>>(cols, vals, nnzA,
      bufA, bufA, nullptr, 1.f, 0.f, bufB, bufD);
  spmm_bf16<<<dim3(NN, 2), 256, 0, stream>>>(cols, vals, nnzA,
      bufB, bufD, bufA, 2.f, -1.f, bufC, bufE);

  // gate: mats [x0, S0x1, S0x2, S1x1, S1x2]; writes r*hx into bufA, u -> ubuf
  gate_mfma<<<NN, 256, 0, stream>>>(bufA, bufB, bufC, bufD, bufE,
                                    Wt, bias, hx, bufA, ubuf);

  // gconv2 diffusion on x0' = concat(inputs, r*hx)
  spmm_bf16<<<dim3(NN, 2), 256, 0, stream>>>(cols, vals, nnzA,
      bufA, bufA, nullptr, 1.f, 0.f, bufC, bufE);
  spmm_bf16<<<dim3(NN, 2), 256, 0, stream>>>(cols, vals, nnzA,
      bufC, bufE, bufA, 2.f, -1.f, bufD, bufF);

  // candidate + final combine
  cand_mfma<<<NN, 256, 0, stream>>>(bufA, bufC, bufD, bufE, bufF,
                                    W2t, b2, hx, ubuf, out);
}